// Round 7
// baseline (222.388 us; speedup 1.0000x reference)
//
#include <hip/hip_runtime.h>
#include <math.h>

#define NB 8
#define ND 64
#define ND2 32
#define NN 65536
#define NC 32
#define NSPLIT 2
constexpr float EPSF = 1e-12f;

// ws layout (floats):
// sums2   [NSPLIT][NB][NC][ND] @0      (32768)
// countsf [NSPLIT][NB][NC]     @32768  (512)

// Per-(b, d-pair, split) cluster sums, zero atomics: each thread owns a private
// LDS float2 column bins2[*][tid]. One b64 RMW accumulates TWO rows (2d, 2d+1)
// of the same point (same label) -> DS cycles/value halved vs b32, and labels
// are fetched 33x not 65x. Bank = 2*tid%32, label-independent, conflict-free.
// Iteration prefetch: next loads issued before the DS block.
// Slice d==ND2 accumulates {1,1} -> counts (exact in fp32); also zeroes out[0].
__global__ __launch_bounds__(256) void k_sums(const float* __restrict__ data,
                                              const int* __restrict__ labels,
                                              float* __restrict__ sums2,
                                              float* __restrict__ countsf,
                                              float* __restrict__ out) {
    const int d = blockIdx.x, split = blockIdx.y, b = blockIdx.z;
    const int tid = threadIdx.x;
    __shared__ float2 bins2[NC][256];  // 64 KB
    for (int i = tid; i < NC * 256 / 2; i += 256)
        ((float4*)bins2)[i] = float4{0.f, 0.f, 0.f, 0.f};
    if (d == ND2 && split == 0 && b == 0 && tid == 0) out[0] = 0.f;  // d_out is poisoned
    __syncthreads();
    const int Q = NN / NSPLIT / 4;  // 8192 float4/int4 per (b,split) per row
    const int4* lp = (const int4*)(labels + (size_t)b * NN) + (size_t)split * Q;
    if (d == ND2) {  // count slice (labels only)
        for (int i = tid; i < Q; i += 1024) {
            int4 c0 = lp[i], c1 = lp[i + 256], c2 = lp[i + 512], c3 = lp[i + 768];
            float2* bt = &bins2[0][tid];
#define CNT(cc) { float2 v = bt[(cc) * 256]; v.x += 1.f; v.y += 1.f; bt[(cc) * 256] = v; }
            CNT(c0.x & 31) CNT(c0.y & 31) CNT(c0.z & 31) CNT(c0.w & 31)
            CNT(c1.x & 31) CNT(c1.y & 31) CNT(c1.z & 31) CNT(c1.w & 31)
            CNT(c2.x & 31) CNT(c2.y & 31) CNT(c2.z & 31) CNT(c2.w & 31)
            CNT(c3.x & 31) CNT(c3.y & 31) CNT(c3.z & 31) CNT(c3.w & 31)
#undef CNT
        }
    } else {
        const float4* xa = (const float4*)(data + ((size_t)b * ND + 2 * d) * NN) + (size_t)split * Q;
        const float4* xb = (const float4*)(data + ((size_t)b * ND + 2 * d + 1) * NN) + (size_t)split * Q;
        float4 a0 = xa[tid], a1 = xa[tid + 256], a2 = xa[tid + 512], a3 = xa[tid + 768];
        float4 b0 = xb[tid], b1 = xb[tid + 256], b2 = xb[tid + 512], b3 = xb[tid + 768];
        int4  c0 = lp[tid], c1 = lp[tid + 256], c2 = lp[tid + 512], c3 = lp[tid + 768];
        float2* bt = &bins2[0][tid];
        for (int i = tid;;) {
            const int nxt = i + 1024;
            const bool more = (nxt < Q);
            float4 na0, na1, na2, na3, nb0, nb1, nb2, nb3;
            int4 e0, e1, e2, e3;
            if (more) {  // issue next-iter loads BEFORE the DS block
                na0 = xa[nxt]; na1 = xa[nxt + 256]; na2 = xa[nxt + 512]; na3 = xa[nxt + 768];
                nb0 = xb[nxt]; nb1 = xb[nxt + 256]; nb2 = xb[nxt + 512]; nb3 = xb[nxt + 768];
                e0 = lp[nxt]; e1 = lp[nxt + 256]; e2 = lp[nxt + 512]; e3 = lp[nxt + 768];
            }
#define ACC(cc, va, vb) { float2 v = bt[(cc) * 256]; v.x += (va); v.y += (vb); bt[(cc) * 256] = v; }
            ACC(c0.x & 31, a0.x, b0.x) ACC(c0.y & 31, a0.y, b0.y)
            ACC(c0.z & 31, a0.z, b0.z) ACC(c0.w & 31, a0.w, b0.w)
            ACC(c1.x & 31, a1.x, b1.x) ACC(c1.y & 31, a1.y, b1.y)
            ACC(c1.z & 31, a1.z, b1.z) ACC(c1.w & 31, a1.w, b1.w)
            ACC(c2.x & 31, a2.x, b2.x) ACC(c2.y & 31, a2.y, b2.y)
            ACC(c2.z & 31, a2.z, b2.z) ACC(c2.w & 31, a2.w, b2.w)
            ACC(c3.x & 31, a3.x, b3.x) ACC(c3.y & 31, a3.y, b3.y)
            ACC(c3.z & 31, a3.z, b3.z) ACC(c3.w & 31, a3.w, b3.w)
#undef ACC
            if (!more) break;
            a0 = na0; a1 = na1; a2 = na2; a3 = na3;
            b0 = nb0; b1 = nb1; b2 = nb2; b3 = nb3;
            c0 = e0; c1 = e1; c2 = e2; c3 = e3;
            i = nxt;
        }
    }
    __syncthreads();
    // column reduce: thread (c=tid>>3, j=tid&7) sums bins2[c][i*8+j]
    const int c = tid >> 3, j = tid & 7;
    float sx = 0.f, sy = 0.f;
#pragma unroll
    for (int i = 0; i < 32; ++i) {
        float2 v = bins2[c][i * 8 + j];
        sx += v.x; sy += v.y;
    }
    sx += __shfl_xor(sx, 1); sy += __shfl_xor(sy, 1);
    sx += __shfl_xor(sx, 2); sy += __shfl_xor(sy, 2);
    sx += __shfl_xor(sx, 4); sy += __shfl_xor(sy, 4);
    if (j == 0) {
        if (d == ND2) countsf[((size_t)split * NB + b) * NC + c] = sx;
        else {
            sums2[(((size_t)split * NB + b) * NC + c) * ND + 2 * d]     = sx;
            sums2[(((size_t)split * NB + b) * NC + c) * ND + 2 * d + 1] = sy;
        }
    }
}

// Fused: every block redundantly builds centers (16KB L2-resident sums2 read),
// c2, weights in LDS; chunk-0 blocks also compute dist+reg terms; all blocks
// accumulate their var partial into out via native global f32 atomic add.
__global__ __launch_bounds__(256) void k_var(const float* __restrict__ data,
                                             const int* __restrict__ labels,
                                             const float* __restrict__ sums2,
                                             const float* __restrict__ countsf,
                                             float* __restrict__ out) {
    const int chunk = blockIdx.x, b = blockIdx.y, tid = threadIdx.x;
    __shared__ float2 cT2[32][NC];  // 8 KB: (d2,c) -> {center[2d2][c], center[2d2+1][c]}
    __shared__ float c2s[NC], wsm[NC], invs[NC], reals[NC];
    __shared__ float ncl_s;
    __shared__ float red[4], red2[4];
    const int n0 = chunk * 1024 + tid * 4;
    int4 cv = *(const int4*)(labels + (size_t)b * NN + n0);  // issue early
    if (tid < NC) {
        float cnt = countsf[b * NC + tid] + countsf[(NB + b) * NC + tid];
        reals[tid] = cnt > 0.f ? 1.f : 0.f;
        invs[tid]  = cnt > 0.f ? 1.f / cnt : 0.f;
    }
    __syncthreads();
    if (tid == 0) {
        float nc = 0.f;
        for (int c = 0; c < NC; ++c) nc += reals[c];
        ncl_s = nc;
    }
    for (int i = tid; i < NC * ND; i += 256) {
        int c = i >> 6, d = i & 63;
        float v = (sums2[((size_t)b * NC + c) * ND + d] +
                   sums2[((size_t)(NB + b) * NC + c) * ND + d]) * invs[c];
        ((float*)cT2)[(d >> 1) * 64 + c * 2 + (d & 1)] = v;  // float2-packed transpose
    }
    __syncthreads();
    {
        int c = tid >> 3, j = tid & 7;
        float s = 0.f;
#pragma unroll
        for (int i = 0; i < 8; ++i) {
            int d = j * 8 + i;
            float v = ((float*)cT2)[(d >> 1) * 64 + c * 2 + (d & 1)];
            s = fmaf(v, v, s);
        }
        s += __shfl_xor(s, 1);
        s += __shfl_xor(s, 2);
        s += __shfl_xor(s, 4);
        if (j == 0) c2s[c] = s;
    }
    __syncthreads();  // c2s, ncl_s visible
    const float ncl = ncl_s;
    if (tid < NC) wsm[tid] = invs[tid] / (ncl * (float)NB);
    __syncthreads();  // wsm visible
    if (chunk == 0) {  // dist + reg terms, once per batch
        float acc = 0.f;
#pragma unroll
        for (int k = 0; k < 4; ++k) {
            int p = tid * 4 + k;
            int c = p >> 5, e = p & (NC - 1);
            if (c != e && reals[c] > 0.f && reals[e] > 0.f) {
                float cd = 0.f;
                for (int d2 = 0; d2 < 32; ++d2) {
                    float2 a = cT2[d2][c], bb = cT2[d2][e];
                    cd = fmaf(a.x, bb.x, cd);
                    cd = fmaf(a.y, bb.y, cd);
                }
                float cd2 = fmaxf(c2s[c] + c2s[e] - 2.f * cd, EPSF);
                float m = fmaxf(2.f - sqrtf(cd2), 0.f);
                acc += m * m;
            }
        }
        const float pairs = ncl * (ncl - 1.f) * 0.5f;
        acc = acc / (2.f * pairs * (float)NB);
        if (tid < NC) {  // delta_reg = sqrt(64) = 8
            float cn = sqrtf(fmaxf(c2s[tid], EPSF));
            float m = fmaxf(cn - 8.f, 0.f);
            acc += (m * m) / (ncl * (float)NB);
        }
#pragma unroll
        for (int o = 32; o >= 1; o >>= 1) acc += __shfl_xor(acc, o);
        if ((tid & 63) == 0) red[tid >> 6] = acc;
        __syncthreads();
        if (tid == 0) unsafeAtomicAdd(out, red[0] + red[1] + red[2] + red[3]);
    }
    // var term: per point, d2 = x2 + c2 - 2*dot (same expanded form + EPS as ref)
    const int cx = cv.x & 31, cy = cv.y & 31, cz = cv.z & 31, cw = cv.w & 31;
    const float* base = data + (size_t)b * ND * NN + n0;
    float dp0 = 0, dp1 = 0, dp2 = 0, dp3 = 0, q0 = 0, q1 = 0, q2 = 0, q3 = 0;
#pragma unroll 8
    for (int d2 = 0; d2 < 32; ++d2) {
        float4 xa = *(const float4*)(base + (size_t)(2 * d2) * NN);
        float4 xb = *(const float4*)(base + (size_t)(2 * d2 + 1) * NN);
        float2 ca = cT2[d2][cx], cb = cT2[d2][cy], cc = cT2[d2][cz], cd = cT2[d2][cw];
        dp0 = fmaf(xa.x, ca.x, dp0); dp0 = fmaf(xb.x, ca.y, dp0);
        dp1 = fmaf(xa.y, cb.x, dp1); dp1 = fmaf(xb.y, cb.y, dp1);
        dp2 = fmaf(xa.z, cc.x, dp2); dp2 = fmaf(xb.z, cc.y, dp2);
        dp3 = fmaf(xa.w, cd.x, dp3); dp3 = fmaf(xb.w, cd.y, dp3);
        q0 = fmaf(xa.x, xa.x, q0); q0 = fmaf(xb.x, xb.x, q0);
        q1 = fmaf(xa.y, xa.y, q1); q1 = fmaf(xb.y, xb.y, q1);
        q2 = fmaf(xa.z, xa.z, q2); q2 = fmaf(xb.z, xb.z, q2);
        q3 = fmaf(xa.w, xa.w, q3); q3 = fmaf(xb.w, xb.w, q3);
    }
    float t0 = fmaxf(q0 + c2s[cx] - 2.f * dp0, EPSF);
    float t1 = fmaxf(q1 + c2s[cy] - 2.f * dp1, EPSF);
    float t2 = fmaxf(q2 + c2s[cz] - 2.f * dp2, EPSF);
    float t3 = fmaxf(q3 + c2s[cw] - 2.f * dp3, EPSF);
    float e0 = fmaxf(sqrtf(t0) - 1.f, 0.f);
    float e1 = fmaxf(sqrtf(t1) - 1.f, 0.f);
    float e2 = fmaxf(sqrtf(t2) - 1.f, 0.f);
    float e3 = fmaxf(sqrtf(t3) - 1.f, 0.f);
    float acc = e0 * e0 * wsm[cx] + e1 * e1 * wsm[cy] + e2 * e2 * wsm[cz] + e3 * e3 * wsm[cw];
#pragma unroll
    for (int o = 32; o >= 1; o >>= 1) acc += __shfl_xor(acc, o);
    if ((tid & 63) == 0) red2[tid >> 6] = acc;
    __syncthreads();
    if (tid == 0) unsafeAtomicAdd(out, red2[0] + red2[1] + red2[2] + red2[3]);
}

extern "C" void kernel_launch(void* const* d_in, const int* in_sizes, int n_in,
                              void* d_out, int out_size, void* d_ws, size_t ws_size,
                              hipStream_t stream) {
    const float* data  = (const float*)d_in[0];
    const int* labels  = (const int*)d_in[1];
    float* out = (float*)d_out;
    float* ws  = (float*)d_ws;
    float* sums2   = ws;          // 32768 floats
    float* countsf = ws + 32768;  // 512 floats

    k_sums<<<dim3(ND2 + 1, NSPLIT, NB), 256, 0, stream>>>(data, labels, sums2, countsf, out);
    k_var<<<dim3(NN / 1024, NB), 256, 0, stream>>>(data, labels, sums2, countsf, out);
}